// Round 1
// baseline (274.805 us; speedup 1.0000x reference)
//
#include <hip/hip_runtime.h>
#include <math.h>

#define IMG_H 512
#define IMG_W 512
#define N_IMG 96            // 32 * 3
#define TW 64               // tile width (output cols)
#define TH 16               // tile height (output rows)
#define HALO 5
#define KS 11
#define TILES_X (IMG_W / TW)          // 8
#define TILES_Y (IMG_H / TH)          // 32
#define TILES_PER_IMG (TILES_X * TILES_Y)   // 256
#define NBLOCKS (N_IMG * TILES_PER_IMG)     // 24576
#define TOTAL_N 25165824.0  // 32*3*512*512

// ---------------- main tile kernel ----------------
__global__ __launch_bounds__(256) void ssim_tile_kernel(
    const float* __restrict__ pred, const float* __restrict__ targ,
    const float* __restrict__ k2d, float* __restrict__ partial)
{
    // halo input tiles (26 rows x 74 cols used; stride 80 for alignment)
    __shared__ __align__(16) float sP[26][80];
    __shared__ __align__(16) float sT[26][80];
    // horizontally convolved maps (26 rows x 64 cols)
    __shared__ __align__(16) float hX [26][64];
    __shared__ __align__(16) float hY [26][64];
    __shared__ __align__(16) float hXX[26][64];
    __shared__ __align__(16) float hYY[26][64];
    __shared__ __align__(16) float hXY[26][64];

    const int tid = threadIdx.x;
    const int bid = blockIdx.x;
    const int img = bid >> 8;          // / 256 tiles per image
    const int tin = bid & 255;
    const int ty  = tin >> 3;          // / TILES_X
    const int tx  = tin & 7;
    const int y0  = ty * TH;
    const int x0  = tx * TW;

    // exact 1D gaussian from the provided 2D kernel: k2d[5][j] = g5 * g[j]
    float g[KS];
    {
        const float g5 = sqrtf(k2d[5 * KS + 5]);
        const float inv = 1.0f / g5;
        #pragma unroll
        for (int j = 0; j < KS; ++j) g[j] = k2d[5 * KS + j] * inv;
    }

    const float* __restrict__ Pimg = pred + (size_t)img * (IMG_H * IMG_W);
    const float* __restrict__ Timg = targ + (size_t)img * (IMG_H * IMG_W);

    // ---- stage 0: load halo tile (zero padding outside image) ----
    for (int i = tid; i < 26 * 80; i += 256) {
        const int r = i / 80;
        const int c = i - r * 80;
        if (c < 74) {
            const int gr = y0 - HALO + r;
            const int gc = x0 - HALO + c;
            const bool ok = (gr >= 0) && (gr < IMG_H) && (gc >= 0) && (gc < IMG_W);
            float pv = 0.0f, tv = 0.0f;
            if (ok) {
                const int o = gr * IMG_W + gc;
                pv = Pimg[o];
                tv = Timg[o];
            }
            sP[r][c] = pv;
            sT[r][c] = tv;
        }
    }
    __syncthreads();

    // ---- stage 1: horizontal 11-tap pass over 5 maps ----
    // 26 rows x 16 col-groups of 4 => 416 units
    for (int u = tid; u < 26 * 16; u += 256) {
        const int r = u >> 4;
        const int c = (u & 15) << 2;

        float p[16], t[16];
        #pragma unroll
        for (int q = 0; q < 4; ++q) {
            const float4 vp = *(const float4*)&sP[r][c + 4 * q];
            const float4 vt = *(const float4*)&sT[r][c + 4 * q];
            p[4*q+0] = vp.x; p[4*q+1] = vp.y; p[4*q+2] = vp.z; p[4*q+3] = vp.w;
            t[4*q+0] = vt.x; t[4*q+1] = vt.y; t[4*q+2] = vt.z; t[4*q+3] = vt.w;
        }

        float ax[4], ay[4], axx[4], ayy[4], axy[4];
        #pragma unroll
        for (int k = 0; k < 4; ++k) { ax[k]=0.f; ay[k]=0.f; axx[k]=0.f; ayy[k]=0.f; axy[k]=0.f; }

        #pragma unroll
        for (int k = 0; k < 4; ++k) {
            #pragma unroll
            for (int j = 0; j < KS; ++j) {
                const float pv = p[k + j];
                const float tv = t[k + j];
                const float gp = g[j] * pv;
                const float gt = g[j] * tv;
                ax[k] += gp;
                ay[k] += gt;
                axx[k] = fmaf(gp, pv, axx[k]);
                ayy[k] = fmaf(gt, tv, ayy[k]);
                axy[k] = fmaf(gp, tv, axy[k]);
            }
        }
        *(float4*)&hX [r][c] = make_float4(ax[0],  ax[1],  ax[2],  ax[3]);
        *(float4*)&hY [r][c] = make_float4(ay[0],  ay[1],  ay[2],  ay[3]);
        *(float4*)&hXX[r][c] = make_float4(axx[0], axx[1], axx[2], axx[3]);
        *(float4*)&hYY[r][c] = make_float4(ayy[0], ayy[1], ayy[2], ayy[3]);
        *(float4*)&hXY[r][c] = make_float4(axy[0], axy[1], axy[2], axy[3]);
    }
    __syncthreads();

    // ---- stage 2: vertical 11-tap pass + SSIM formula ----
    // thread -> (col, row-group of 4): 64 cols x 4 groups = 256 threads
    const int col = tid & 63;
    const int rg  = tid >> 6;          // 0..3, output rows rg*4 .. rg*4+3

    float vx[14], vy[14], vxx[14], vyy[14], vxy[14];
    #pragma unroll
    for (int i = 0; i < 14; ++i) {
        const int r = rg * 4 + i;
        vx[i]  = hX [r][col];
        vy[i]  = hY [r][col];
        vxx[i] = hXX[r][col];
        vyy[i] = hYY[r][col];
        vxy[i] = hXY[r][col];
    }

    const float C1 = 1.0e-4f;   // (0.01*1)^2
    const float C2 = 9.0e-4f;   // (0.03*1)^2
    float lsum = 0.0f;
    #pragma unroll
    for (int k = 0; k < 4; ++k) {
        float mx = 0.f, my = 0.f, sxx = 0.f, syy = 0.f, sxy = 0.f;
        #pragma unroll
        for (int j = 0; j < KS; ++j) {
            mx  = fmaf(g[j], vx [k + j], mx);
            my  = fmaf(g[j], vy [k + j], my);
            sxx = fmaf(g[j], vxx[k + j], sxx);
            syy = fmaf(g[j], vyy[k + j], syy);
            sxy = fmaf(g[j], vxy[k + j], sxy);
        }
        const float mx2 = mx * mx;
        const float my2 = my * my;
        const float mxy = mx * my;
        const float s2x  = sxx - mx2;
        const float s2y  = syy - my2;
        const float s2xy = sxy - mxy;
        const float num = (2.0f * mxy + C1) * (2.0f * s2xy + C2);
        const float den = (mx2 + my2 + C1) * (s2x + s2y + C2);
        lsum += num / den;
    }

    // ---- block reduction ----
    #pragma unroll
    for (int off = 32; off > 0; off >>= 1)
        lsum += __shfl_down(lsum, off, 64);

    __shared__ float wsum[4];
    const int lane = tid & 63;
    const int wid  = tid >> 6;
    if (lane == 0) wsum[wid] = lsum;
    __syncthreads();
    if (tid == 0)
        partial[bid] = wsum[0] + wsum[1] + wsum[2] + wsum[3];
}

// ---------------- final reduction ----------------
__global__ __launch_bounds__(256) void ssim_reduce_kernel(
    const float* __restrict__ partial, int n, float* __restrict__ out)
{
    const int tid = threadIdx.x;
    double s = 0.0;
    for (int i = tid; i < n; i += 256) s += (double)partial[i];

    #pragma unroll
    for (int off = 32; off > 0; off >>= 1)
        s += __shfl_down(s, off, 64);

    __shared__ double wsum[4];
    const int lane = tid & 63;
    const int wid  = tid >> 6;
    if (lane == 0) wsum[wid] = s;
    __syncthreads();
    if (tid == 0) {
        const double total = wsum[0] + wsum[1] + wsum[2] + wsum[3];
        out[0] = (float)(1.0 - total / TOTAL_N);
    }
}

extern "C" void kernel_launch(void* const* d_in, const int* in_sizes, int n_in,
                              void* d_out, int out_size, void* d_ws, size_t ws_size,
                              hipStream_t stream) {
    const float* pred = (const float*)d_in[0];
    const float* targ = (const float*)d_in[1];
    const float* k2d  = (const float*)d_in[2];
    float* out = (float*)d_out;
    float* ws  = (float*)d_ws;   // NBLOCKS partial sums

    ssim_tile_kernel<<<NBLOCKS, 256, 0, stream>>>(pred, targ, k2d, ws);
    ssim_reduce_kernel<<<1, 256, 0, stream>>>(ws, NBLOCKS, out);
}